// Round 4
// baseline (346.026 us; speedup 1.0000x reference)
//
#include <hip/hip_runtime.h>
#include <hip/hip_bf16.h>
#include <stdint.h>

// Problem constants (hard-coded): B=4, S=2048, D=1024, H=16, HD=64
#define B_   4
#define S_   2048
#define D_   1024
#define H_   16
#define HD_  64
#define BH_  (B_*H_)      // 64
#define MROWS (B_*S_)     // 8192

typedef short  short8  __attribute__((ext_vector_type(8)));
typedef float  floatx4 __attribute__((ext_vector_type(4)));

__device__ __forceinline__ ushort f2bf(float f) {
    union { float f; uint32_t u; } v; v.f = f;
    uint32_t u = v.u;
    return (ushort)((u + 0x7FFFu + ((u >> 16) & 1u)) >> 16);   // RNE
}
__device__ __forceinline__ float bf2f(ushort b) {
    union { uint32_t u; float f; } v; v.u = ((uint32_t)b) << 16;
    return v.f;
}
__device__ __forceinline__ float u2f(uint32_t u) {
    union { uint32_t u; float f; } v; v.u = u; return v.f;
}
__device__ __forceinline__ uint32_t f2u(float f) {
    union { float f; uint32_t u; } v; v.f = f; return v.u;
}

// async global->LDS, 16 B per lane. LDS dest must be wave-uniform base + lane*16.
__device__ __forceinline__ void gl_lds16(const ushort* g, ushort* l) {
    __builtin_amdgcn_global_load_lds(
        (const __attribute__((address_space(1))) unsigned int*)g,
        (__attribute__((address_space(3))) unsigned int*)l,
        16, 0, 0);
}

// ---------------------------------------------------------------- converts
__global__ void k_f32_to_bf16(const float* __restrict__ in, ushort* __restrict__ out, int n) {
    int i = (blockIdx.x * blockDim.x + threadIdx.x) * 4;
    if (i + 3 < n) {
        float4 f = *(const float4*)(in + i);
        ushort4 o; o.x = f2bf(f.x); o.y = f2bf(f.y); o.z = f2bf(f.z); o.w = f2bf(f.w);
        *(ushort4*)(out + i) = o;
    }
}

// in: fp32 [R][C] -> out: bf16 [C][R]
__global__ void k_transpose_to_bf16(const float* __restrict__ in, ushort* __restrict__ out,
                                    int R, int C) {
    __shared__ float tile[32][33];
    int bx = blockIdx.x * 32;   // C offset
    int by = blockIdx.y * 32;   // R offset
    int tx = threadIdx.x;       // 0..31
    int ty = threadIdx.y;       // 0..7
    #pragma unroll
    for (int j = 0; j < 32; j += 8)
        tile[ty + j][tx] = in[(size_t)(by + ty + j) * C + bx + tx];
    __syncthreads();
    #pragma unroll
    for (int j = 0; j < 32; j += 8)
        out[(size_t)(bx + ty + j) * R + by + tx] = f2bf(tile[tx][ty + j]);
}

// bf16 [bh][s][HD] -> bf16 [bh][HD][S]
__global__ void k_vtrans(const ushort* __restrict__ Vb, ushort* __restrict__ VbT) {
    __shared__ __align__(16) ushort t[64 * 72];
    int bh = blockIdx.x >> 5;
    int s0 = (blockIdx.x & 31) * 64;
    int tid = threadIdx.x;
    int ss = tid >> 2, c0 = (tid & 3) * 16;
    size_t base = (size_t)bh * S_ * HD_;
    *(uint4*)&t[ss * 72 + c0]     = *(const uint4*)&Vb[base + (size_t)(s0 + ss) * HD_ + c0];
    *(uint4*)&t[ss * 72 + c0 + 8] = *(const uint4*)&Vb[base + (size_t)(s0 + ss) * HD_ + c0 + 8];
    __syncthreads();
    int hd = tid >> 2, q0 = (tid & 3) * 16;
    ushort tmp[16];
    #pragma unroll
    for (int e = 0; e < 16; e++) tmp[e] = t[(q0 + e) * 72 + hd];
    size_t obase = (size_t)bh * HD_ * S_ + (size_t)hd * S_ + s0 + q0;
    *(uint4*)&VbT[obase]     = *(const uint4*)&tmp[0];
    *(uint4*)&VbT[obase + 8] = *(const uint4*)&tmp[8];
}

// ---------------------------------------------------------------- GEMM (m97-style async staging)
#define BM 128
#define BN 128
#define BK 32
#define LDT 32   // UNPADDED: required by global_load_lds lane-contiguous dest

template<int EPI>
__global__ __launch_bounds__(256)
void k_gemm(const ushort* __restrict__ A, const ushort* __restrict__ Bt,
            float* __restrict__ outF,
            ushort* __restrict__ q_out, ushort* __restrict__ k_out, ushort* __restrict__ v_out,
            int M, int N, int K) {
    __shared__ __align__(16) ushort As[BM * LDT];
    __shared__ __align__(16) ushort Bs[BN * LDT];
    int tid  = threadIdx.x;
    int lane = tid & 63;
    int wave = tid >> 6;
    int quad = lane >> 4;
    int l16  = lane & 15;
    int bm = blockIdx.y * BM;
    int bn = blockIdx.x * BN;
    int wm = (wave >> 1) * 64;
    int wn = (wave & 1) * 64;

    floatx4 acc[4][4] = {};

    for (int k0 = 0; k0 < K; k0 += BK) {
        __syncthreads();
        #pragma unroll
        for (int p = 0; p < 2; p++) {
            int c   = p * 256 + tid;
            int row = c >> 2;
            int kc  = (c & 3) << 3;
            gl_lds16(&A[(size_t)(bm + row) * K + k0 + kc],  &As[c * 8]);
            gl_lds16(&Bt[(size_t)(bn + row) * K + k0 + kc], &Bs[c * 8]);
        }
        __syncthreads();
        short8 af[4], bf[4];
        #pragma unroll
        for (int mt = 0; mt < 4; mt++)
            af[mt] = *(const short8*)&As[(wm + mt * 16 + l16) * LDT + quad * 8];
        #pragma unroll
        for (int nt = 0; nt < 4; nt++)
            bf[nt] = *(const short8*)&Bs[(wn + nt * 16 + l16) * LDT + quad * 8];
        #pragma unroll
        for (int mt = 0; mt < 4; mt++)
            #pragma unroll
            for (int nt = 0; nt < 4; nt++)
                acc[mt][nt] = __builtin_amdgcn_mfma_f32_16x16x32_bf16(af[mt], bf[nt], acc[mt][nt], 0, 0, 0);
    }

    #pragma unroll
    for (int mt = 0; mt < 4; mt++)
        #pragma unroll
        for (int nt = 0; nt < 4; nt++)
            #pragma unroll
            for (int r = 0; r < 4; r++) {
                int row = bm + wm + mt * 16 + quad * 4 + r;
                int col = bn + wn + nt * 16 + l16;
                float v = acc[mt][nt][r];
                if (EPI == 0) {
                    int which = col >> 10;
                    int rem   = col & 1023;
                    int h  = rem >> 6, hd = rem & 63;
                    int b  = row >> 11, s  = row & 2047;
                    size_t idx = ((size_t)(b * H_ + h) * S_ + s) * HD_ + hd;
                    ushort bv = f2bf(v);
                    ushort* dst = (which == 0) ? q_out : (which == 1) ? k_out : v_out;
                    dst[idx] = bv;
                } else {
                    outF[(size_t)row * N + col] = v;
                }
            }
}

// ---------------------------------------------------------------- RoPE (in-place)
// Q additionally pre-scaled by 0.125 (exact in bf16) so attention skips the
// per-score multiply.
__global__ void k_rope(ushort* __restrict__ Q, ushort* __restrict__ Kv,
                       const float* __restrict__ cosT, const float* __restrict__ sinT) {
    int wid  = (blockIdx.x * 256 + threadIdx.x) >> 6;
    int lane = threadIdx.x & 63;
    int s  = wid & (S_ - 1);
    int bh = wid >> 11;
    int i  = lane & 31;
    float c  = cosT[s * 32 + i];
    float sn = sinT[s * 32 + i];
    size_t base = ((size_t)bh * S_ + s) * HD_;

    uint32_t uq = *(const uint32_t*)&Q[base + 2 * i];
    float x1 = u2f(uq << 16), x2 = u2f(uq & 0xFFFF0000u);
    float o  = (lane < 32) ? (x1 * c - x2 * sn) : (x1 * sn + x2 * c);
    Q[base + lane] = f2bf(o * 0.125f);

    uint32_t uk = *(const uint32_t*)&Kv[base + 2 * i];
    x1 = u2f(uk << 16); x2 = u2f(uk & 0xFFFF0000u);
    o  = (lane < 32) ? (x1 * c - x2 * sn) : (x1 * sn + x2 * c);
    Kv[base + lane] = f2bf(o);
}

// ---------------------------------------------------------------- flash attention v4
// QK computed operand-swapped: sc = MFMA(A=K, B=Q) -> C[key][qrow], so each
// lane's 4 score values are key-contiguous: P stores as packed ds_write_b64
// (8 per tile vs 32 scalar b16). Row-sum is one scalar per lane (qrow=l16),
// reduced with 2 shuffles at the end. Q pre-scaled by 1/8 in k_rope.
// grid: 1024 blocks = 16 qblk (reversed) x 64 bh; 256 threads (4 waves).
__global__ __launch_bounds__(256, 4)
void k_attn(const ushort* __restrict__ Q, const ushort* __restrict__ K,
            const ushort* __restrict__ VT, ushort* __restrict__ O) {
    __shared__ __align__(16) ushort Ksp[2][64 * 32];   // plane h: [key][hd-half]
    __shared__ __align__(16) ushort Vtp[2][64 * 32];   // plane k2: [hd][key-half]
    __shared__ __align__(16) ushort Pst[4][32 * 72];   // per-wave [qrow][key] (+pad)
    __shared__ float Lw[4][32];

    int tid  = threadIdx.x;
    int lane = tid & 63;
    int wave = tid >> 6;
    int quad = lane >> 4;
    int l16  = lane & 15;

    int bh   = blockIdx.x & 63;
    int qblk = 15 - (blockIdx.x >> 6);     // expensive blocks dispatch first
    int qb0  = qblk * 128;
    size_t hbase = (size_t)bh * S_ * HD_;
    size_t vbase = (size_t)bh * HD_ * S_;

    int mrow[2] = { qb0 + wave * 16, qb0 + 64 + wave * 16 };

    short8 qf[2][2];
    #pragma unroll
    for (int m = 0; m < 2; m++)
        #pragma unroll
        for (int h = 0; h < 2; h++)
            qf[m][h] = *(const short8*)&Q[hbase + (size_t)(mrow[m] + l16) * HD_ + quad * 8 + h * 32];

    floatx4 acc[2][4] = {};
    float lsum[2] = {0.0f, 0.0f};

    int crow = tid >> 2;          // chunk row (key for K, hd for V)
    int coff = (tid & 3) * 8;     // chunk elem offset within 32-col plane

    int nk = 2 * qblk + 2;
    for (int kb = 0; kb < nk; kb++) {
        int k0 = kb * 64;
        __syncthreads();
        #pragma unroll
        for (int h = 0; h < 2; h++)
            gl_lds16(&K[hbase + (size_t)(k0 + crow) * HD_ + h * 32 + coff], &Ksp[h][tid * 8]);
        #pragma unroll
        for (int k2 = 0; k2 < 2; k2++)
            gl_lds16(&VT[vbase + (size_t)crow * S_ + k0 + k2 * 32 + coff], &Vtp[k2][tid * 8]);
        __syncthreads();

        bool act[2] = { k0 <= mrow[0] + 15, k0 <= mrow[1] + 15 };

        // K fragments hoisted: read once, used by both m-tiles
        short8 kf[4][2];
        #pragma unroll
        for (int kt = 0; kt < 4; kt++)
            #pragma unroll
            for (int h = 0; h < 2; h++)
                kf[kt][h] = *(const short8*)&Ksp[h][(kt * 16 + l16) * 32 + quad * 8];

        // ---- QK + softmax-numerator + P store
        #pragma unroll
        for (int m = 0; m < 2; m++) {
            if (!act[m]) continue;
            floatx4 sc[4] = {};
            #pragma unroll
            for (int kt = 0; kt < 4; kt++)
                #pragma unroll
                for (int h = 0; h < 2; h++)
                    sc[kt] = __builtin_amdgcn_mfma_f32_16x16x32_bf16(kf[kt][h], qf[m][h], sc[kt], 0, 0, 0);
            bool needMask = (k0 + 63 > mrow[m]);
            int qr = mrow[m] + l16;
            #pragma unroll
            for (int kt = 0; kt < 4; kt++) {
                float p[4];
                #pragma unroll
                for (int r = 0; r < 4; r++) {
                    float v = __expf(sc[kt][r]);
                    if (needMask) {
                        int kc = k0 + kt * 16 + quad * 4 + r;
                        if (kc > qr) v = 0.0f;
                    }
                    p[r] = v;
                }
                lsum[m] += (p[0] + p[1]) + (p[2] + p[3]);
                uint2 pk;
                pk.x = __builtin_amdgcn_perm(f2u(p[1]) + 0x8000u, f2u(p[0]) + 0x8000u, 0x07060302u);
                pk.y = __builtin_amdgcn_perm(f2u(p[3]) + 0x8000u, f2u(p[2]) + 0x8000u, 0x07060302u);
                *(uint2*)&Pst[wave][(m * 16 + l16) * 72 + kt * 16 + quad * 4] = pk;
            }
        }

        // ---- PV
        #pragma unroll
        for (int k2 = 0; k2 < 2; k2++) {
            short8 vb[4];
            #pragma unroll
            for (int nt = 0; nt < 4; nt++)
                vb[nt] = *(const short8*)&Vtp[k2][(nt * 16 + l16) * 32 + quad * 8];
            #pragma unroll
            for (int m = 0; m < 2; m++) {
                if (!act[m]) continue;
                short8 pa = *(const short8*)&Pst[wave][(m * 16 + l16) * 72 + k2 * 32 + quad * 8];
                #pragma unroll
                for (int nt = 0; nt < 4; nt++)
                    acc[m][nt] = __builtin_amdgcn_mfma_f32_16x16x32_bf16(pa, vb[nt], acc[m][nt], 0, 0, 0);
            }
        }
    }

    // reduce row-sums across quads (lanes l16, l16+16, l16+32, l16+48)
    #pragma unroll
    for (int m = 0; m < 2; m++) {
        lsum[m] += __shfl_xor(lsum[m], 16);
        lsum[m] += __shfl_xor(lsum[m], 32);
        if (quad == 0) Lw[wave][m * 16 + l16] = lsum[m];
    }

    int b = bh >> 4, h = bh & 15;
    #pragma unroll
    for (int m = 0; m < 2; m++)
        #pragma unroll
        for (int r = 0; r < 4; r++) {
            float inv = 1.0f / Lw[wave][m * 16 + quad * 4 + r];
            int qr = mrow[m] + quad * 4 + r;
            #pragma unroll
            for (int nt = 0; nt < 4; nt++)
                O[((size_t)(b * S_ + qr)) * D_ + h * HD_ + nt * 16 + l16] = f2bf(acc[m][nt][r] * inv);
        }
}

// ---------------------------------------------------------------- launch
extern "C" void kernel_launch(void* const* d_in, const int* in_sizes, int n_in,
                              void* d_out, int out_size, void* d_ws, size_t ws_size,
                              hipStream_t stream) {
    const float* x    = (const float*)d_in[0];
    const float* cosT = (const float*)d_in[1];
    const float* sinT = (const float*)d_in[2];
    // d_in[3] = mask : causal, computed analytically — never read
    const float* Wqkv = (const float*)d_in[4];
    const float* Wout = (const float*)d_in[5];
    float* out = (float*)d_out;

    ushort* ws = (ushort*)d_ws;
    ushort* Xbf    = ws;                           // 8192*1024 (dead after GEMM0)
    ushort* WqkvT  = Xbf    + (size_t)MROWS * D_;  // 3072*1024
    ushort* WoutT  = WqkvT  + (size_t)3 * D_ * D_; // 1024*1024
    ushort* Qb     = WoutT  + (size_t)D_ * D_;     // 64*2048*64
    ushort* Kb     = Qb     + (size_t)BH_ * S_ * HD_;
    ushort* Vb     = Kb     + (size_t)BH_ * S_ * HD_;
    ushort* VbT    = Vb     + (size_t)BH_ * S_ * HD_;
    ushort* AO     = Xbf;                          // alias: Xbf dead after GEMM0

    k_f32_to_bf16<<<(MROWS * D_) / 1024, 256, 0, stream>>>(x, Xbf, MROWS * D_);
    k_transpose_to_bf16<<<dim3(3 * D_ / 32, D_ / 32), dim3(32, 8), 0, stream>>>(Wqkv, WqkvT, D_, 3 * D_);
    k_transpose_to_bf16<<<dim3(D_ / 32, D_ / 32), dim3(32, 8), 0, stream>>>(Wout, WoutT, D_, D_);
    k_gemm<0><<<dim3(3 * D_ / BN, MROWS / BM), 256, 0, stream>>>(Xbf, WqkvT, nullptr, Qb, Kb, Vb,
                                                                 MROWS, 3 * D_, D_);
    k_rope<<<(BH_ * S_ * 64) / 256, 256, 0, stream>>>(Qb, Kb, cosT, sinT);
    k_vtrans<<<BH_ * 32, 256, 0, stream>>>(Vb, VbT);
    k_attn<<<1024, 256, 0, stream>>>(Qb, Kb, VbT, AO);
    k_gemm<1><<<dim3(D_ / BN, MROWS / BM), 256, 0, stream>>>(AO, WoutT, out, nullptr, nullptr, nullptr,
                                                             MROWS, D_, D_);
}

// Round 5
// 333.668 us; speedup vs baseline: 1.0370x; 1.0370x over previous
//
#include <hip/hip_runtime.h>
#include <hip/hip_bf16.h>
#include <stdint.h>

// Problem constants (hard-coded): B=4, S=2048, D=1024, H=16, HD=64
#define B_   4
#define S_   2048
#define D_   1024
#define H_   16
#define HD_  64
#define BH_  (B_*H_)      // 64
#define MROWS (B_*S_)     // 8192

typedef short  short8  __attribute__((ext_vector_type(8)));
typedef float  floatx4 __attribute__((ext_vector_type(4)));

__device__ __forceinline__ ushort f2bf(float f) {
    union { float f; uint32_t u; } v; v.f = f;
    uint32_t u = v.u;
    return (ushort)((u + 0x7FFFu + ((u >> 16) & 1u)) >> 16);   // RNE
}
__device__ __forceinline__ float u2f(uint32_t u) {
    union { uint32_t u; float f; } v; v.u = u; return v.f;
}
__device__ __forceinline__ uint32_t f2u(float f) {
    union { float f; uint32_t u; } v; v.f = f; return v.u;
}

// async global->LDS, 16 B per lane. LDS dest must be wave-uniform base + lane*16.
__device__ __forceinline__ void gl_lds16(const ushort* g, ushort* l) {
    __builtin_amdgcn_global_load_lds(
        (const __attribute__((address_space(1))) unsigned int*)g,
        (__attribute__((address_space(3))) unsigned int*)l,
        16, 0, 0);
}

// ---------------------------------------------------------------- converts
__global__ void k_f32_to_bf16(const float* __restrict__ in, ushort* __restrict__ out, int n) {
    int i = (blockIdx.x * blockDim.x + threadIdx.x) * 4;
    if (i + 3 < n) {
        float4 f = *(const float4*)(in + i);
        ushort4 o; o.x = f2bf(f.x); o.y = f2bf(f.y); o.z = f2bf(f.z); o.w = f2bf(f.w);
        *(ushort4*)(out + i) = o;
    }
}

// in: fp32 [R][C] -> out: bf16 [C][R]
__global__ void k_transpose_to_bf16(const float* __restrict__ in, ushort* __restrict__ out,
                                    int R, int C) {
    __shared__ float tile[32][33];
    int bx = blockIdx.x * 32;   // C offset
    int by = blockIdx.y * 32;   // R offset
    int tx = threadIdx.x;       // 0..31
    int ty = threadIdx.y;       // 0..7
    #pragma unroll
    for (int j = 0; j < 32; j += 8)
        tile[ty + j][tx] = in[(size_t)(by + ty + j) * C + bx + tx];
    __syncthreads();
    #pragma unroll
    for (int j = 0; j < 32; j += 8)
        out[(size_t)(bx + ty + j) * R + by + tx] = f2bf(tile[tx][ty + j]);
}

// bf16 [bh][s][HD] -> bf16 [bh][HD][S]
__global__ void k_vtrans(const ushort* __restrict__ Vb, ushort* __restrict__ VbT) {
    __shared__ __align__(16) ushort t[64 * 72];
    int bh = blockIdx.x >> 5;
    int s0 = (blockIdx.x & 31) * 64;
    int tid = threadIdx.x;
    int ss = tid >> 2, c0 = (tid & 3) * 16;
    size_t base = (size_t)bh * S_ * HD_;
    *(uint4*)&t[ss * 72 + c0]     = *(const uint4*)&Vb[base + (size_t)(s0 + ss) * HD_ + c0];
    *(uint4*)&t[ss * 72 + c0 + 8] = *(const uint4*)&Vb[base + (size_t)(s0 + ss) * HD_ + c0 + 8];
    __syncthreads();
    int hd = tid >> 2, q0 = (tid & 3) * 16;
    ushort tmp[16];
    #pragma unroll
    for (int e = 0; e < 16; e++) tmp[e] = t[(q0 + e) * 72 + hd];
    size_t obase = (size_t)bh * HD_ * S_ + (size_t)hd * S_ + s0 + q0;
    *(uint4*)&VbT[obase]     = *(const uint4*)&tmp[0];
    *(uint4*)&VbT[obase + 8] = *(const uint4*)&tmp[8];
}

// ---------------------------------------------------------------- GEMM (m97-style async staging)
#define BM 128
#define BN 128
#define BK 32
#define LDT 32   // UNPADDED: required by global_load_lds lane-contiguous dest

template<int EPI>
__global__ __launch_bounds__(256)
void k_gemm(const ushort* __restrict__ A, const ushort* __restrict__ Bt,
            float* __restrict__ outF,
            ushort* __restrict__ q_out, ushort* __restrict__ k_out, ushort* __restrict__ v_out,
            int M, int N, int K) {
    __shared__ __align__(16) ushort As[BM * LDT];
    __shared__ __align__(16) ushort Bs[BN * LDT];
    int tid  = threadIdx.x;
    int lane = tid & 63;
    int wave = tid >> 6;
    int quad = lane >> 4;
    int l16  = lane & 15;
    int bm = blockIdx.y * BM;
    int bn = blockIdx.x * BN;
    int wm = (wave >> 1) * 64;
    int wn = (wave & 1) * 64;

    floatx4 acc[4][4] = {};

    for (int k0 = 0; k0 < K; k0 += BK) {
        __syncthreads();
        #pragma unroll
        for (int p = 0; p < 2; p++) {
            int c   = p * 256 + tid;
            int row = c >> 2;
            int kc  = (c & 3) << 3;
            gl_lds16(&A[(size_t)(bm + row) * K + k0 + kc],  &As[c * 8]);
            gl_lds16(&Bt[(size_t)(bn + row) * K + k0 + kc], &Bs[c * 8]);
        }
        __syncthreads();
        short8 af[4], bf[4];
        #pragma unroll
        for (int mt = 0; mt < 4; mt++)
            af[mt] = *(const short8*)&As[(wm + mt * 16 + l16) * LDT + quad * 8];
        #pragma unroll
        for (int nt = 0; nt < 4; nt++)
            bf[nt] = *(const short8*)&Bs[(wn + nt * 16 + l16) * LDT + quad * 8];
        #pragma unroll
        for (int mt = 0; mt < 4; mt++)
            #pragma unroll
            for (int nt = 0; nt < 4; nt++)
                acc[mt][nt] = __builtin_amdgcn_mfma_f32_16x16x32_bf16(af[mt], bf[nt], acc[mt][nt], 0, 0, 0);
    }

    #pragma unroll
    for (int mt = 0; mt < 4; mt++)
        #pragma unroll
        for (int nt = 0; nt < 4; nt++)
            #pragma unroll
            for (int r = 0; r < 4; r++) {
                int row = bm + wm + mt * 16 + quad * 4 + r;
                int col = bn + wn + nt * 16 + l16;
                float v = acc[mt][nt][r];
                if (EPI == 0) {
                    int which = col >> 10;
                    int rem   = col & 1023;
                    int h  = rem >> 6, hd = rem & 63;
                    int b  = row >> 11, s  = row & 2047;
                    size_t idx = ((size_t)(b * H_ + h) * S_ + s) * HD_ + hd;
                    ushort bv = f2bf(v);
                    ushort* dst = (which == 0) ? q_out : (which == 1) ? k_out : v_out;
                    dst[idx] = bv;
                } else {
                    outF[(size_t)row * N + col] = v;
                }
            }
}

// ---------------------------------------------------------------- RoPE (in-place)
// Q pre-scaled by 0.125*log2(e) so attention uses raw exp2 (bare v_exp_f32).
__global__ void k_rope(ushort* __restrict__ Q, ushort* __restrict__ Kv,
                       const float* __restrict__ cosT, const float* __restrict__ sinT) {
    int wid  = (blockIdx.x * 256 + threadIdx.x) >> 6;
    int lane = threadIdx.x & 63;
    int s  = wid & (S_ - 1);
    int bh = wid >> 11;
    int i  = lane & 31;
    float c  = cosT[s * 32 + i];
    float sn = sinT[s * 32 + i];
    size_t base = ((size_t)bh * S_ + s) * HD_;

    uint32_t uq = *(const uint32_t*)&Q[base + 2 * i];
    float x1 = u2f(uq << 16), x2 = u2f(uq & 0xFFFF0000u);
    float o  = (lane < 32) ? (x1 * c - x2 * sn) : (x1 * sn + x2 * c);
    Q[base + lane] = f2bf(o * 0.1803368801f);   // (1/8)*log2(e)

    uint32_t uk = *(const uint32_t*)&Kv[base + 2 * i];
    x1 = u2f(uk << 16); x2 = u2f(uk & 0xFFFF0000u);
    o  = (lane < 32) ? (x1 * c - x2 * sn) : (x1 * sn + x2 * c);
    Kv[base + lane] = f2bf(o);
}

// ---------------------------------------------------------------- flash attention v5
// Operand-swapped QK (C[key][qrow]) -> packed b64 P stores. Row-sums computed
// on the MFMA pipe via a constant ones-fragment B operand (accl), so the
// softmax denominator needs zero VALU/shuffle work. exp2 (Q pre-scaled).
// kf fragments NOT hoisted (R4's hoist spilled to scratch: WRITE_SIZE 2x).
// grid: 1024 blocks = 16 qblk (reversed) x 64 bh; 256 threads (4 waves).
__global__ __launch_bounds__(256, 4)
void k_attn(const ushort* __restrict__ Q, const ushort* __restrict__ K,
            const ushort* __restrict__ VT, ushort* __restrict__ O) {
    __shared__ __align__(16) ushort Ksp[2][64 * 32];   // plane h: [key][hd-half]
    __shared__ __align__(16) ushort Vtp[2][64 * 32];   // plane k2: [hd][key-half]
    __shared__ __align__(16) ushort Pst[4][32 * 72];   // per-wave [qrow][key] (+pad)

    int tid  = threadIdx.x;
    int lane = tid & 63;
    int wave = tid >> 6;
    int quad = lane >> 4;
    int l16  = lane & 15;

    int bh   = blockIdx.x & 63;
    int qblk = 15 - (blockIdx.x >> 6);     // expensive blocks dispatch first
    int qb0  = qblk * 128;
    size_t hbase = (size_t)bh * S_ * HD_;
    size_t vbase = (size_t)bh * HD_ * S_;

    int mrow[2] = { qb0 + wave * 16, qb0 + 64 + wave * 16 };

    short8 qf[2][2];
    #pragma unroll
    for (int m = 0; m < 2; m++)
        #pragma unroll
        for (int h = 0; h < 2; h++)
            qf[m][h] = *(const short8*)&Q[hbase + (size_t)(mrow[m] + l16) * HD_ + quad * 8 + h * 32];

    short8 ones;
    #pragma unroll
    for (int e = 0; e < 8; e++) ones[e] = (short)0x3F80;   // bf16 1.0

    floatx4 acc[2][4] = {};
    floatx4 accl[2] = {};

    int crow = tid >> 2;          // chunk row (key for K, hd for V)
    int coff = (tid & 3) * 8;     // chunk elem offset within 32-col plane

    int nk = 2 * qblk + 2;
    for (int kb = 0; kb < nk; kb++) {
        int k0 = kb * 64;
        __syncthreads();
        #pragma unroll
        for (int h = 0; h < 2; h++)
            gl_lds16(&K[hbase + (size_t)(k0 + crow) * HD_ + h * 32 + coff], &Ksp[h][tid * 8]);
        #pragma unroll
        for (int k2 = 0; k2 < 2; k2++)
            gl_lds16(&VT[vbase + (size_t)crow * S_ + k0 + k2 * 32 + coff], &Vtp[k2][tid * 8]);
        __syncthreads();

        bool act[2] = { k0 <= mrow[0] + 15, k0 <= mrow[1] + 15 };

        // ---- QK + exp2 + packed P store
        #pragma unroll
        for (int m = 0; m < 2; m++) {
            if (!act[m]) continue;
            floatx4 sc[4] = {};
            #pragma unroll
            for (int kt = 0; kt < 4; kt++)
                #pragma unroll
                for (int h = 0; h < 2; h++) {
                    short8 kf = *(const short8*)&Ksp[h][(kt * 16 + l16) * 32 + quad * 8];
                    sc[kt] = __builtin_amdgcn_mfma_f32_16x16x32_bf16(kf, qf[m][h], sc[kt], 0, 0, 0);
                }
            bool needMask = (k0 + 63 > mrow[m]);
            int qr = mrow[m] + l16;
            #pragma unroll
            for (int kt = 0; kt < 4; kt++) {
                float p[4];
                #pragma unroll
                for (int r = 0; r < 4; r++) {
                    float v = exp2f(sc[kt][r]);
                    if (needMask) {
                        int kc = k0 + kt * 16 + quad * 4 + r;
                        if (kc > qr) v = 0.0f;
                    }
                    p[r] = v;
                }
                uint2 pk;
                pk.x = __builtin_amdgcn_perm(f2u(p[1]) + 0x8000u, f2u(p[0]) + 0x8000u, 0x07060302u);
                pk.y = __builtin_amdgcn_perm(f2u(p[3]) + 0x8000u, f2u(p[2]) + 0x8000u, 0x07060302u);
                *(uint2*)&Pst[wave][(m * 16 + l16) * 72 + kt * 16 + quad * 4] = pk;
            }
        }

        // ---- PV (+ row-sum via ones-fragment on the MFMA pipe)
        #pragma unroll
        for (int k2 = 0; k2 < 2; k2++) {
            #pragma unroll
            for (int m = 0; m < 2; m++) {
                if (!act[m]) continue;
                short8 pa = *(const short8*)&Pst[wave][(m * 16 + l16) * 72 + k2 * 32 + quad * 8];
                #pragma unroll
                for (int nt = 0; nt < 4; nt++) {
                    short8 vb = *(const short8*)&Vtp[k2][(nt * 16 + l16) * 32 + quad * 8];
                    acc[m][nt] = __builtin_amdgcn_mfma_f32_16x16x32_bf16(pa, vb, acc[m][nt], 0, 0, 0);
                }
                accl[m] = __builtin_amdgcn_mfma_f32_16x16x32_bf16(pa, ones, accl[m], 0, 0, 0);
            }
        }
    }

    int b = bh >> 4, h = bh & 15;
    #pragma unroll
    for (int m = 0; m < 2; m++)
        #pragma unroll
        for (int r = 0; r < 4; r++) {
            float inv = 1.0f / accl[m][r];
            int qr = mrow[m] + quad * 4 + r;
            #pragma unroll
            for (int nt = 0; nt < 4; nt++)
                O[((size_t)(b * S_ + qr)) * D_ + h * HD_ + nt * 16 + l16] = f2bf(acc[m][nt][r] * inv);
        }
}

// ---------------------------------------------------------------- launch
extern "C" void kernel_launch(void* const* d_in, const int* in_sizes, int n_in,
                              void* d_out, int out_size, void* d_ws, size_t ws_size,
                              hipStream_t stream) {
    const float* x    = (const float*)d_in[0];
    const float* cosT = (const float*)d_in[1];
    const float* sinT = (const float*)d_in[2];
    // d_in[3] = mask : causal, computed analytically — never read
    const float* Wqkv = (const float*)d_in[4];
    const float* Wout = (const float*)d_in[5];
    float* out = (float*)d_out;

    ushort* ws = (ushort*)d_ws;
    ushort* Xbf    = ws;                           // 8192*1024 (dead after GEMM0)
    ushort* WqkvT  = Xbf    + (size_t)MROWS * D_;  // 3072*1024
    ushort* WoutT  = WqkvT  + (size_t)3 * D_ * D_; // 1024*1024
    ushort* Qb     = WoutT  + (size_t)D_ * D_;     // 64*2048*64
    ushort* Kb     = Qb     + (size_t)BH_ * S_ * HD_;
    ushort* Vb     = Kb     + (size_t)BH_ * S_ * HD_;
    ushort* VbT    = Vb     + (size_t)BH_ * S_ * HD_;
    ushort* AO     = Xbf;                          // alias: Xbf dead after GEMM0

    k_f32_to_bf16<<<(MROWS * D_) / 1024, 256, 0, stream>>>(x, Xbf, MROWS * D_);
    k_transpose_to_bf16<<<dim3(3 * D_ / 32, D_ / 32), dim3(32, 8), 0, stream>>>(Wqkv, WqkvT, D_, 3 * D_);
    k_transpose_to_bf16<<<dim3(D_ / 32, D_ / 32), dim3(32, 8), 0, stream>>>(Wout, WoutT, D_, D_);
    k_gemm<0><<<dim3(3 * D_ / BN, MROWS / BM), 256, 0, stream>>>(Xbf, WqkvT, nullptr, Qb, Kb, Vb,
                                                                 MROWS, 3 * D_, D_);
    k_rope<<<(BH_ * S_ * 64) / 256, 256, 0, stream>>>(Qb, Kb, cosT, sinT);
    k_vtrans<<<BH_ * 32, 256, 0, stream>>>(Vb, VbT);
    k_attn<<<1024, 256, 0, stream>>>(Qb, Kb, VbT, AO);
    k_gemm<1><<<dim3(D_ / BN, MROWS / BM), 256, 0, stream>>>(AO, WoutT, out, nullptr, nullptr, nullptr,
                                                             MROWS, D_, D_);
}

// Round 7
// 311.286 us; speedup vs baseline: 1.1116x; 1.0719x over previous
//
#include <hip/hip_runtime.h>
#include <hip/hip_bf16.h>
#include <stdint.h>

// Problem constants (hard-coded): B=4, S=2048, D=1024, H=16, HD=64
#define B_   4
#define S_   2048
#define D_   1024
#define H_   16
#define HD_  64
#define BH_  (B_*H_)      // 64
#define MROWS (B_*S_)     // 8192

typedef short  short8  __attribute__((ext_vector_type(8)));
typedef float  floatx4 __attribute__((ext_vector_type(4)));

__device__ __forceinline__ ushort f2bf(float f) {
    union { float f; uint32_t u; } v; v.f = f;
    uint32_t u = v.u;
    return (ushort)((u + 0x7FFFu + ((u >> 16) & 1u)) >> 16);   // RNE
}
__device__ __forceinline__ float u2f(uint32_t u) {
    union { uint32_t u; float f; } v; v.u = u; return v.f;
}
__device__ __forceinline__ uint32_t f2u(float f) {
    union { float f; uint32_t u; } v; v.f = f; return v.u;
}

// async global->LDS, 16 B per lane. LDS dest MUST be wave-uniform base +
// lane*16 (m104/m108) — any swizzling must happen on the GLOBAL address.
__device__ __forceinline__ void gl_lds16(const ushort* g, ushort* l) {
    __builtin_amdgcn_global_load_lds(
        (const __attribute__((address_space(1))) unsigned int*)g,
        (__attribute__((address_space(3))) unsigned int*)l,
        16, 0, 0);
}

// ---------------------------------------------------------------- converts
__global__ void k_f32_to_bf16(const float* __restrict__ in, ushort* __restrict__ out, int n) {
    int i = (blockIdx.x * blockDim.x + threadIdx.x) * 4;
    if (i + 3 < n) {
        float4 f = *(const float4*)(in + i);
        ushort4 o; o.x = f2bf(f.x); o.y = f2bf(f.y); o.z = f2bf(f.z); o.w = f2bf(f.w);
        *(ushort4*)(out + i) = o;
    }
}

// in: fp32 [R][C] -> out: bf16 [C][R]
__global__ void k_transpose_to_bf16(const float* __restrict__ in, ushort* __restrict__ out,
                                    int R, int C) {
    __shared__ float tile[32][33];
    int bx = blockIdx.x * 32;   // C offset
    int by = blockIdx.y * 32;   // R offset
    int tx = threadIdx.x;       // 0..31
    int ty = threadIdx.y;       // 0..7
    #pragma unroll
    for (int j = 0; j < 32; j += 8)
        tile[ty + j][tx] = in[(size_t)(by + ty + j) * C + bx + tx];
    __syncthreads();
    #pragma unroll
    for (int j = 0; j < 32; j += 8)
        out[(size_t)(bx + ty + j) * R + by + tx] = f2bf(tile[tx][ty + j]);
}

// bf16 [bh][s][HD] -> bf16 [bh][HD][S]
__global__ void k_vtrans(const ushort* __restrict__ Vb, ushort* __restrict__ VbT) {
    __shared__ __align__(16) ushort t[64 * 72];
    int bh = blockIdx.x >> 5;
    int s0 = (blockIdx.x & 31) * 64;
    int tid = threadIdx.x;
    int ss = tid >> 2, c0 = (tid & 3) * 16;
    size_t base = (size_t)bh * S_ * HD_;
    *(uint4*)&t[ss * 72 + c0]     = *(const uint4*)&Vb[base + (size_t)(s0 + ss) * HD_ + c0];
    *(uint4*)&t[ss * 72 + c0 + 8] = *(const uint4*)&Vb[base + (size_t)(s0 + ss) * HD_ + c0 + 8];
    __syncthreads();
    int hd = tid >> 2, q0 = (tid & 3) * 16;
    ushort tmp[16];
    #pragma unroll
    for (int e = 0; e < 16; e++) tmp[e] = t[(q0 + e) * 72 + hd];
    size_t obase = (size_t)bh * HD_ * S_ + (size_t)hd * S_ + s0 + q0;
    *(uint4*)&VbT[obase]     = *(const uint4*)&tmp[0];
    *(uint4*)&VbT[obase + 8] = *(const uint4*)&tmp[8];
}

// ---------------------------------------------------------------- GEMM v7
// Async staging, XOR swizzle on the GLOBAL side: LDS chunk position q of row r
// holds global chunk q^(r&7). LDS dest stays linear (DMA-legal). Fragment
// reads at chunk c^(l16&7) are then conflict-free (2-way max). BK=64.
#define BM 128
#define BN 128
#define BK 64

template<int EPI>
__global__ __launch_bounds__(256)
void k_gemm(const ushort* __restrict__ A, const ushort* __restrict__ Bt,
            float* __restrict__ outF,
            ushort* __restrict__ q_out, ushort* __restrict__ k_out, ushort* __restrict__ v_out,
            int M, int N, int K) {
    __shared__ __align__(16) ushort As[BM * 64];
    __shared__ __align__(16) ushort Bs[BN * 64];
    int tid  = threadIdx.x;
    int lane = tid & 63;
    int wave = tid >> 6;
    int quad = lane >> 4;
    int l16  = lane & 15;
    int bm = blockIdx.y * BM;
    int bn = blockIdx.x * BN;
    int wm = (wave >> 1) * 64;
    int wn = (wave & 1) * 64;

    floatx4 acc[4][4] = {};

    for (int k0 = 0; k0 < K; k0 += BK) {
        __syncthreads();
        #pragma unroll
        for (int i = 0; i < 4; i++) {
            int c   = i * 256 + tid;          // 1024 chunks per matrix
            int row = c >> 3;
            int gc  = (c & 7) ^ (row & 7);    // permuted global chunk
            gl_lds16(&A[(size_t)(bm + row) * K + k0 + gc * 8],  &As[c * 8]);
            gl_lds16(&Bt[(size_t)(bn + row) * K + k0 + gc * 8], &Bs[c * 8]);
        }
        __syncthreads();
        #pragma unroll
        for (int kk = 0; kk < 2; kk++) {
            short8 af[4], bf[4];
            #pragma unroll
            for (int mt = 0; mt < 4; mt++)
                af[mt] = *(const short8*)&As[(wm + mt * 16 + l16) * 64 +
                                             (((kk * 4 + quad) ^ (l16 & 7)) << 3)];
            #pragma unroll
            for (int nt = 0; nt < 4; nt++)
                bf[nt] = *(const short8*)&Bs[(wn + nt * 16 + l16) * 64 +
                                             (((kk * 4 + quad) ^ (l16 & 7)) << 3)];
            #pragma unroll
            for (int mt = 0; mt < 4; mt++)
                #pragma unroll
                for (int nt = 0; nt < 4; nt++)
                    acc[mt][nt] = __builtin_amdgcn_mfma_f32_16x16x32_bf16(af[mt], bf[nt], acc[mt][nt], 0, 0, 0);
        }
    }

    #pragma unroll
    for (int mt = 0; mt < 4; mt++)
        #pragma unroll
        for (int nt = 0; nt < 4; nt++)
            #pragma unroll
            for (int r = 0; r < 4; r++) {
                int row = bm + wm + mt * 16 + quad * 4 + r;
                int col = bn + wn + nt * 16 + l16;
                float v = acc[mt][nt][r];
                if (EPI == 0) {
                    int which = col >> 10;
                    int rem   = col & 1023;
                    int h  = rem >> 6, hd = rem & 63;
                    int b  = row >> 11, s  = row & 2047;
                    size_t idx = ((size_t)(b * H_ + h) * S_ + s) * HD_ + hd;
                    ushort bv = f2bf(v);
                    ushort* dst = (which == 0) ? q_out : (which == 1) ? k_out : v_out;
                    dst[idx] = bv;
                } else {
                    outF[(size_t)row * N + col] = v;
                }
            }
}

// ---------------------------------------------------------------- RoPE (in-place)
// Q pre-scaled by 0.125*log2(e) so attention uses raw exp2 (bare v_exp_f32).
__global__ void k_rope(ushort* __restrict__ Q, ushort* __restrict__ Kv,
                       const float* __restrict__ cosT, const float* __restrict__ sinT) {
    int wid  = (blockIdx.x * 256 + threadIdx.x) >> 6;
    int lane = threadIdx.x & 63;
    int s  = wid & (S_ - 1);
    int bh = wid >> 11;
    int i  = lane & 31;
    float c  = cosT[s * 32 + i];
    float sn = sinT[s * 32 + i];
    size_t base = ((size_t)bh * S_ + s) * HD_;

    uint32_t uq = *(const uint32_t*)&Q[base + 2 * i];
    float x1 = u2f(uq << 16), x2 = u2f(uq & 0xFFFF0000u);
    float o  = (lane < 32) ? (x1 * c - x2 * sn) : (x1 * sn + x2 * c);
    Q[base + lane] = f2bf(o * 0.1803368801f);   // (1/8)*log2(e)

    uint32_t uk = *(const uint32_t*)&Kv[base + 2 * i];
    x1 = u2f(uk << 16); x2 = u2f(uk & 0xFFFF0000u);
    o  = (lane < 32) ? (x1 * c - x2 * sn) : (x1 * sn + x2 * c);
    Kv[base + lane] = f2bf(o);
}

// ---------------------------------------------------------------- flash attention v7
// Operand-swapped QK (C[key][qrow]) -> packed b64 P stores. MFMA-pipe row sums
// (ones fragment). exp2 with Q pre-scaled. Global-side XOR swizzle for K/V
// staging (LDS dest linear = DMA-legal); P-tile swizzled via normal ds_write.
// grid: 1024 blocks = 16 qblk (reversed) x 64 bh; 256 threads (4 waves).
__global__ __launch_bounds__(256, 4)
void k_attn(const ushort* __restrict__ Q, const ushort* __restrict__ K,
            const ushort* __restrict__ VT, ushort* __restrict__ O) {
    __shared__ __align__(16) ushort Ks[64 * 64];       // [key][hd]  swizzled
    __shared__ __align__(16) ushort Vt[64 * 64];       // [hd][key]  swizzled
    __shared__ __align__(16) ushort Pst[4][32 * 64];   // per-wave [qrow][key] swizzled

    int tid  = threadIdx.x;
    int lane = tid & 63;
    int wave = tid >> 6;
    int quad = lane >> 4;
    int l16  = lane & 15;

    int bh   = blockIdx.x & 63;
    int qblk = 15 - (blockIdx.x >> 6);     // expensive blocks dispatch first
    int qb0  = qblk * 128;
    size_t hbase = (size_t)bh * S_ * HD_;
    size_t vbase = (size_t)bh * HD_ * S_;

    int mrow[2] = { qb0 + wave * 16, qb0 + 64 + wave * 16 };

    short8 qf[2][2];
    #pragma unroll
    for (int m = 0; m < 2; m++)
        #pragma unroll
        for (int h = 0; h < 2; h++)
            qf[m][h] = *(const short8*)&Q[hbase + (size_t)(mrow[m] + l16) * HD_ + quad * 8 + h * 32];

    short8 ones;
    #pragma unroll
    for (int e = 0; e < 8; e++) ones[e] = (short)0x3F80;   // bf16 1.0

    floatx4 acc[2][4] = {};
    floatx4 accl[2] = {};

    int nk = 2 * qblk + 2;
    for (int kb = 0; kb < nk; kb++) {
        int k0 = kb * 64;
        __syncthreads();
        #pragma unroll
        for (int i = 0; i < 2; i++) {
            int c   = i * 256 + tid;          // 512 chunks per tile
            int row = c >> 3;
            int gc  = (c & 7) ^ (row & 7);    // permuted global chunk
            gl_lds16(&K[hbase + (size_t)(k0 + row) * HD_ + gc * 8], &Ks[c * 8]);
            gl_lds16(&VT[vbase + (size_t)row * S_ + k0 + gc * 8],   &Vt[c * 8]);
        }
        __syncthreads();

        bool act[2] = { k0 <= mrow[0] + 15, k0 <= mrow[1] + 15 };

        // ---- QK + exp2 + packed swizzled P store
        #pragma unroll
        for (int m = 0; m < 2; m++) {
            if (!act[m]) continue;
            floatx4 sc[4] = {};
            #pragma unroll
            for (int kt = 0; kt < 4; kt++)
                #pragma unroll
                for (int h = 0; h < 2; h++) {
                    short8 kf = *(const short8*)&Ks[(kt * 16 + l16) * 64 +
                                                    (((h * 4 + quad) ^ (l16 & 7)) << 3)];
                    sc[kt] = __builtin_amdgcn_mfma_f32_16x16x32_bf16(kf, qf[m][h], sc[kt], 0, 0, 0);
                }
            bool needMask = (k0 + 63 > mrow[m]);
            int qr = mrow[m] + l16;
            #pragma unroll
            for (int kt = 0; kt < 4; kt++) {
                float p[4];
                #pragma unroll
                for (int r = 0; r < 4; r++) {
                    float v = exp2f(sc[kt][r]);
                    if (needMask) {
                        int kc = k0 + kt * 16 + quad * 4 + r;
                        if (kc > qr) v = 0.0f;
                    }
                    p[r] = v;
                }
                uint2 pk;
                pk.x = __builtin_amdgcn_perm(f2u(p[1]) + 0x8000u, f2u(p[0]) + 0x8000u, 0x07060302u);
                pk.y = __builtin_amdgcn_perm(f2u(p[3]) + 0x8000u, f2u(p[2]) + 0x8000u, 0x07060302u);
                int pc = (kt * 4 + quad) ^ (l16 & 14);
                *(uint2*)&Pst[wave][(m * 16 + l16) * 64 + pc * 4] = pk;
            }
        }

        // ---- PV (+ MFMA-pipe row sums), V-fragments hoisted per k2
        #pragma unroll
        for (int k2 = 0; k2 < 2; k2++) {
            short8 vb[4];
            #pragma unroll
            for (int nt = 0; nt < 4; nt++)
                vb[nt] = *(const short8*)&Vt[(nt * 16 + l16) * 64 +
                                             (((k2 * 4 + quad) ^ (l16 & 7)) << 3)];
            #pragma unroll
            for (int m = 0; m < 2; m++) {
                if (!act[m]) continue;
                int pe = (k2 * 8 + quad * 2) ^ (l16 & 14);
                short8 pa = *(const short8*)&Pst[wave][(m * 16 + l16) * 64 + pe * 4];
                #pragma unroll
                for (int nt = 0; nt < 4; nt++)
                    acc[m][nt] = __builtin_amdgcn_mfma_f32_16x16x32_bf16(pa, vb[nt], acc[m][nt], 0, 0, 0);
                accl[m] = __builtin_amdgcn_mfma_f32_16x16x32_bf16(pa, ones, accl[m], 0, 0, 0);
            }
        }
    }

    int b = bh >> 4, h = bh & 15;
    #pragma unroll
    for (int m = 0; m < 2; m++)
        #pragma unroll
        for (int r = 0; r < 4; r++) {
            float inv = 1.0f / accl[m][r];
            int qr = mrow[m] + quad * 4 + r;
            #pragma unroll
            for (int nt = 0; nt < 4; nt++)
                O[((size_t)(b * S_ + qr)) * D_ + h * HD_ + nt * 16 + l16] = f2bf(acc[m][nt][r] * inv);
        }
}

// ---------------------------------------------------------------- launch
extern "C" void kernel_launch(void* const* d_in, const int* in_sizes, int n_in,
                              void* d_out, int out_size, void* d_ws, size_t ws_size,
                              hipStream_t stream) {
    const float* x    = (const float*)d_in[0];
    const float* cosT = (const float*)d_in[1];
    const float* sinT = (const float*)d_in[2];
    // d_in[3] = mask : causal, computed analytically — never read
    const float* Wqkv = (const float*)d_in[4];
    const float* Wout = (const float*)d_in[5];
    float* out = (float*)d_out;

    ushort* ws = (ushort*)d_ws;
    ushort* Xbf    = ws;                           // 8192*1024 (dead after GEMM0)
    ushort* WqkvT  = Xbf    + (size_t)MROWS * D_;  // 3072*1024
    ushort* WoutT  = WqkvT  + (size_t)3 * D_ * D_; // 1024*1024
    ushort* Qb     = WoutT  + (size_t)D_ * D_;     // 64*2048*64
    ushort* Kb     = Qb     + (size_t)BH_ * S_ * HD_;
    ushort* Vb     = Kb     + (size_t)BH_ * S_ * HD_;
    ushort* VbT    = Vb     + (size_t)BH_ * S_ * HD_;
    ushort* AO     = Xbf;                          // alias: Xbf dead after GEMM0

    k_f32_to_bf16<<<(MROWS * D_) / 1024, 256, 0, stream>>>(x, Xbf, MROWS * D_);
    k_transpose_to_bf16<<<dim3(3 * D_ / 32, D_ / 32), dim3(32, 8), 0, stream>>>(Wqkv, WqkvT, D_, 3 * D_);
    k_transpose_to_bf16<<<dim3(D_ / 32, D_ / 32), dim3(32, 8), 0, stream>>>(Wout, WoutT, D_, D_);
    k_gemm<0><<<dim3(3 * D_ / BN, MROWS / BM), 256, 0, stream>>>(Xbf, WqkvT, nullptr, Qb, Kb, Vb,
                                                                 MROWS, 3 * D_, D_);
    k_rope<<<(BH_ * S_ * 64) / 256, 256, 0, stream>>>(Qb, Kb, cosT, sinT);
    k_vtrans<<<BH_ * 32, 256, 0, stream>>>(Vb, VbT);
    k_attn<<<1024, 256, 0, stream>>>(Qb, Kb, VbT, AO);
    k_gemm<1><<<dim3(D_ / BN, MROWS / BM), 256, 0, stream>>>(AO, WoutT, out, nullptr, nullptr, nullptr,
                                                             MROWS, D_, D_);
}

// Round 8
// 307.333 us; speedup vs baseline: 1.1259x; 1.0129x over previous
//
#include <hip/hip_runtime.h>
#include <hip/hip_bf16.h>
#include <stdint.h>

// Problem constants (hard-coded): B=4, S=2048, D=1024, H=16, HD=64
#define B_   4
#define S_   2048
#define D_   1024
#define H_   16
#define HD_  64
#define BH_  (B_*H_)      // 64
#define MROWS (B_*S_)     // 8192

typedef short  short8  __attribute__((ext_vector_type(8)));
typedef float  floatx4 __attribute__((ext_vector_type(4)));

__device__ __forceinline__ ushort f2bf(float f) {
    union { float f; uint32_t u; } v; v.f = f;
    uint32_t u = v.u;
    return (ushort)((u + 0x7FFFu + ((u >> 16) & 1u)) >> 16);   // RNE
}
__device__ __forceinline__ float u2f(uint32_t u) {
    union { uint32_t u; float f; } v; v.u = u; return v.f;
}
__device__ __forceinline__ uint32_t f2u(float f) {
    union { float f; uint32_t u; } v; v.f = f; return v.u;
}

// async global->LDS, 16 B per lane. LDS dest MUST be wave-uniform base +
// lane*16 (m104/m108) — any swizzling must happen on the GLOBAL address.
__device__ __forceinline__ void gl_lds16(const ushort* g, ushort* l) {
    __builtin_amdgcn_global_load_lds(
        (const __attribute__((address_space(1))) unsigned int*)g,
        (__attribute__((address_space(3))) unsigned int*)l,
        16, 0, 0);
}

// ---------------------------------------------------------------- fused prep
// blocks [0,3072): Wqkv^T->bf16 ; [3072,4096): Wout^T->bf16 ; [4096,12288): x->bf16
__global__ __launch_bounds__(256)
void k_prep(const float* __restrict__ x, const float* __restrict__ Wqkv,
            const float* __restrict__ Wout,
            ushort* __restrict__ Xbf, ushort* __restrict__ WqkvT, ushort* __restrict__ WoutT) {
    __shared__ float tile[32][33];
    int blk = blockIdx.x;
    int tid = threadIdx.x;
    if (blk >= 4096) {
        int i = (blk - 4096) * 1024 + tid * 4;
        float4 f = *(const float4*)(x + i);
        ushort4 o; o.x = f2bf(f.x); o.y = f2bf(f.y); o.z = f2bf(f.z); o.w = f2bf(f.w);
        *(ushort4*)(Xbf + i) = o;
        return;
    }
    const float* in; ushort* out; int R, C, bx, by;
    if (blk < 3072) { in = Wqkv; out = WqkvT; R = D_; C = 3 * D_; bx = (blk % 96) * 32; by = (blk / 96) * 32; }
    else            { int b2 = blk - 3072; in = Wout; out = WoutT; R = D_; C = D_; bx = (b2 % 32) * 32; by = (b2 / 32) * 32; }
    int tx = tid & 31, ty = tid >> 5;
    #pragma unroll
    for (int j = 0; j < 32; j += 8)
        tile[ty + j][tx] = in[(size_t)(by + ty + j) * C + bx + tx];
    __syncthreads();
    #pragma unroll
    for (int j = 0; j < 32; j += 8)
        out[(size_t)(bx + ty + j) * R + by + tx] = f2bf(tile[tx][ty + j]);
}

// ---------------------------------------------------------------- GEMM (async + global-side XOR swizzle)
#define BM 128
#define BN 128
#define BK 64

template<int EPI>
__global__ __launch_bounds__(256)
void k_gemm(const ushort* __restrict__ A, const ushort* __restrict__ Bt,
            float* __restrict__ outF,
            ushort* __restrict__ q_out, ushort* __restrict__ k_out, ushort* __restrict__ v_out,
            int M, int N, int K) {
    __shared__ __align__(16) ushort As[BM * 64];
    __shared__ __align__(16) ushort Bs[BN * 64];
    int tid  = threadIdx.x;
    int lane = tid & 63;
    int wave = tid >> 6;
    int quad = lane >> 4;
    int l16  = lane & 15;
    int bm = blockIdx.y * BM;
    int bn = blockIdx.x * BN;
    int wm = (wave >> 1) * 64;
    int wn = (wave & 1) * 64;

    floatx4 acc[4][4] = {};

    for (int k0 = 0; k0 < K; k0 += BK) {
        __syncthreads();
        #pragma unroll
        for (int i = 0; i < 4; i++) {
            int c   = i * 256 + tid;
            int row = c >> 3;
            int gc  = (c & 7) ^ (row & 7);    // permuted global chunk
            gl_lds16(&A[(size_t)(bm + row) * K + k0 + gc * 8],  &As[c * 8]);
            gl_lds16(&Bt[(size_t)(bn + row) * K + k0 + gc * 8], &Bs[c * 8]);
        }
        __syncthreads();
        #pragma unroll
        for (int kk = 0; kk < 2; kk++) {
            short8 af[4], bf[4];
            #pragma unroll
            for (int mt = 0; mt < 4; mt++)
                af[mt] = *(const short8*)&As[(wm + mt * 16 + l16) * 64 +
                                             (((kk * 4 + quad) ^ (l16 & 7)) << 3)];
            #pragma unroll
            for (int nt = 0; nt < 4; nt++)
                bf[nt] = *(const short8*)&Bs[(wn + nt * 16 + l16) * 64 +
                                             (((kk * 4 + quad) ^ (l16 & 7)) << 3)];
            #pragma unroll
            for (int mt = 0; mt < 4; mt++)
                #pragma unroll
                for (int nt = 0; nt < 4; nt++)
                    acc[mt][nt] = __builtin_amdgcn_mfma_f32_16x16x32_bf16(af[mt], bf[nt], acc[mt][nt], 0, 0, 0);
        }
    }

    #pragma unroll
    for (int mt = 0; mt < 4; mt++)
        #pragma unroll
        for (int nt = 0; nt < 4; nt++)
            #pragma unroll
            for (int r = 0; r < 4; r++) {
                int row = bm + wm + mt * 16 + quad * 4 + r;
                int col = bn + wn + nt * 16 + l16;
                float v = acc[mt][nt][r];
                if (EPI == 0) {
                    int which = col >> 10;
                    int rem   = col & 1023;
                    int h  = rem >> 6, hd = rem & 63;
                    int b  = row >> 11, s  = row & 2047;
                    size_t idx = ((size_t)(b * H_ + h) * S_ + s) * HD_ + hd;
                    ushort bv = f2bf(v);
                    ushort* dst = (which == 0) ? q_out : (which == 1) ? k_out : v_out;
                    dst[idx] = bv;
                } else {
                    outF[(size_t)row * N + col] = v;
                }
            }
}

// ---------------------------------------------------------------- fused RoPE + V-transpose
// blocks [0,32768): in-place RoPE on Q (pre-scaled by 0.125*log2(e)) and K.
// blocks [32768,34816): V [bh][s][HD] -> VbT [bh][HD][S].
__global__ __launch_bounds__(256)
void k_ropevt(ushort* __restrict__ Q, ushort* __restrict__ Kv,
              const ushort* __restrict__ Vb, ushort* __restrict__ VbT,
              const float* __restrict__ cosT, const float* __restrict__ sinT) {
    __shared__ __align__(16) ushort t[64 * 72];
    int blk = blockIdx.x;
    int tid = threadIdx.x;
    if (blk < 32768) {
        int wid  = (blk * 256 + tid) >> 6;
        int lane = tid & 63;
        int s  = wid & (S_ - 1);
        int bh = wid >> 11;
        int i  = lane & 31;
        float c  = cosT[s * 32 + i];
        float sn = sinT[s * 32 + i];
        size_t base = ((size_t)bh * S_ + s) * HD_;

        uint32_t uq = *(const uint32_t*)&Q[base + 2 * i];
        float x1 = u2f(uq << 16), x2 = u2f(uq & 0xFFFF0000u);
        float o  = (lane < 32) ? (x1 * c - x2 * sn) : (x1 * sn + x2 * c);
        Q[base + lane] = f2bf(o * 0.1803368801f);   // (1/8)*log2(e)

        uint32_t uk = *(const uint32_t*)&Kv[base + 2 * i];
        x1 = u2f(uk << 16); x2 = u2f(uk & 0xFFFF0000u);
        o  = (lane < 32) ? (x1 * c - x2 * sn) : (x1 * sn + x2 * c);
        Kv[base + lane] = f2bf(o);
        return;
    }
    int b2 = blk - 32768;
    int bh = b2 >> 5;
    int s0 = (b2 & 31) * 64;
    int ss = tid >> 2, c0 = (tid & 3) * 16;
    size_t base = (size_t)bh * S_ * HD_;
    *(uint4*)&t[ss * 72 + c0]     = *(const uint4*)&Vb[base + (size_t)(s0 + ss) * HD_ + c0];
    *(uint4*)&t[ss * 72 + c0 + 8] = *(const uint4*)&Vb[base + (size_t)(s0 + ss) * HD_ + c0 + 8];
    __syncthreads();
    int hd = tid >> 2, q0 = (tid & 3) * 16;
    ushort tmp[16];
    #pragma unroll
    for (int e = 0; e < 16; e++) tmp[e] = t[(q0 + e) * 72 + hd];
    size_t obase = (size_t)bh * HD_ * S_ + (size_t)hd * S_ + s0 + q0;
    *(uint4*)&VbT[obase]     = *(const uint4*)&tmp[0];
    *(uint4*)&VbT[obase + 8] = *(const uint4*)&tmp[8];
}

// ---------------------------------------------------------------- flash attention v8
// As v7 (operand-swapped QK, packed b64 P, MFMA-pipe row sums, exp2,
// global-side XOR swizzle) plus:
//  - balanced dispatch: qblk permutation so each round-robin CU stratum gets
//    strips summing to 68 tiles ({15,12,2,1},{14,13,3,0},{11,8,6,5},{10,9,7,4})
//  - staging via incremented per-thread pointers (no per-tile 64-bit rederive)
// grid: 1024 blocks = 16 strip-groups x 64 bh; 256 threads (4 waves).
__global__ __launch_bounds__(256, 4)
void k_attn(const ushort* __restrict__ Q, const ushort* __restrict__ K,
            const ushort* __restrict__ VT, ushort* __restrict__ O) {
    __shared__ __align__(16) ushort Ks[64 * 64];       // [key][hd]  swizzled
    __shared__ __align__(16) ushort Vt[64 * 64];       // [hd][key]  swizzled
    __shared__ __align__(16) ushort Pst[4][32 * 64];   // per-wave [qrow][key] swizzled

    const int PI[16] = {15,14,11,10, 12,13,8,9, 2,3,6,7, 1,0,5,4};

    int tid  = threadIdx.x;
    int lane = tid & 63;
    int wave = tid >> 6;
    int quad = lane >> 4;
    int l16  = lane & 15;

    int bh   = blockIdx.x & 63;
    int qblk = PI[blockIdx.x >> 6];
    int qb0  = qblk * 128;
    size_t hbase = (size_t)bh * S_ * HD_;
    size_t vbase = (size_t)bh * HD_ * S_;

    int mrow[2] = { qb0 + wave * 16, qb0 + 64 + wave * 16 };

    short8 qf[2][2];
    #pragma unroll
    for (int m = 0; m < 2; m++)
        #pragma unroll
        for (int h = 0; h < 2; h++)
            qf[m][h] = *(const short8*)&Q[hbase + (size_t)(mrow[m] + l16) * HD_ + quad * 8 + h * 32];

    short8 ones;
    #pragma unroll
    for (int e = 0; e < 8; e++) ones[e] = (short)0x3F80;   // bf16 1.0

    floatx4 acc[2][4] = {};
    floatx4 accl[2] = {};

    // staging pointers (advance by constant per tile)
    int c0r = tid >> 3;                     // chunk row for i=0 (0..31)
    int c1r = (256 + tid) >> 3;             // chunk row for i=1 (32..63)
    const ushort* kp0 = &K[hbase + (size_t)c0r * HD_ + (((tid & 7) ^ (c0r & 7)) << 3)];
    const ushort* kp1 = &K[hbase + (size_t)c1r * HD_ + (((tid & 7) ^ (c1r & 7)) << 3)];
    const ushort* vp0 = &VT[vbase + (size_t)c0r * S_ + (((tid & 7) ^ (c0r & 7)) << 3)];
    const ushort* vp1 = &VT[vbase + (size_t)c1r * S_ + (((tid & 7) ^ (c1r & 7)) << 3)];

    int nk = 2 * qblk + 2;
    for (int kb = 0; kb < nk; kb++) {
        int k0 = kb * 64;
        __syncthreads();
        gl_lds16(kp0, &Ks[tid * 8]);
        gl_lds16(kp1, &Ks[(256 + tid) * 8]);
        gl_lds16(vp0, &Vt[tid * 8]);
        gl_lds16(vp1, &Vt[(256 + tid) * 8]);
        kp0 += 64 * HD_; kp1 += 64 * HD_; vp0 += 64; vp1 += 64;
        __syncthreads();

        bool act[2] = { k0 <= mrow[0] + 15, k0 <= mrow[1] + 15 };

        // ---- QK + exp2 + packed swizzled P store
        #pragma unroll
        for (int m = 0; m < 2; m++) {
            if (!act[m]) continue;
            floatx4 sc[4] = {};
            #pragma unroll
            for (int kt = 0; kt < 4; kt++)
                #pragma unroll
                for (int h = 0; h < 2; h++) {
                    short8 kf = *(const short8*)&Ks[(kt * 16 + l16) * 64 +
                                                    (((h * 4 + quad) ^ (l16 & 7)) << 3)];
                    sc[kt] = __builtin_amdgcn_mfma_f32_16x16x32_bf16(kf, qf[m][h], sc[kt], 0, 0, 0);
                }
            bool needMask = (k0 + 63 > mrow[m]);
            int qr = mrow[m] + l16;
            #pragma unroll
            for (int kt = 0; kt < 4; kt++) {
                float p[4];
                #pragma unroll
                for (int r = 0; r < 4; r++) {
                    float v = exp2f(sc[kt][r]);
                    if (needMask) {
                        int kc = k0 + kt * 16 + quad * 4 + r;
                        if (kc > qr) v = 0.0f;
                    }
                    p[r] = v;
                }
                uint2 pk;
                pk.x = __builtin_amdgcn_perm(f2u(p[1]) + 0x8000u, f2u(p[0]) + 0x8000u, 0x07060302u);
                pk.y = __builtin_amdgcn_perm(f2u(p[3]) + 0x8000u, f2u(p[2]) + 0x8000u, 0x07060302u);
                int pc = (kt * 4 + quad) ^ (l16 & 14);
                *(uint2*)&Pst[wave][(m * 16 + l16) * 64 + pc * 4] = pk;
            }
        }

        // ---- PV (+ MFMA-pipe row sums)
        #pragma unroll
        for (int k2 = 0; k2 < 2; k2++) {
            short8 vb[4];
            #pragma unroll
            for (int nt = 0; nt < 4; nt++)
                vb[nt] = *(const short8*)&Vt[(nt * 16 + l16) * 64 +
                                             (((k2 * 4 + quad) ^ (l16 & 7)) << 3)];
            #pragma unroll
            for (int m = 0; m < 2; m++) {
                if (!act[m]) continue;
                int pe = (k2 * 8 + quad * 2) ^ (l16 & 14);
                short8 pa = *(const short8*)&Pst[wave][(m * 16 + l16) * 64 + pe * 4];
                #pragma unroll
                for (int nt = 0; nt < 4; nt++)
                    acc[m][nt] = __builtin_amdgcn_mfma_f32_16x16x32_bf16(pa, vb[nt], acc[m][nt], 0, 0, 0);
                accl[m] = __builtin_amdgcn_mfma_f32_16x16x32_bf16(pa, ones, accl[m], 0, 0, 0);
            }
        }
    }

    int b = bh >> 4, h = bh & 15;
    #pragma unroll
    for (int m = 0; m < 2; m++)
        #pragma unroll
        for (int r = 0; r < 4; r++) {
            float inv = 1.0f / accl[m][r];
            int qr = mrow[m] + quad * 4 + r;
            #pragma unroll
            for (int nt = 0; nt < 4; nt++)
                O[((size_t)(b * S_ + qr)) * D_ + h * HD_ + nt * 16 + l16] = f2bf(acc[m][nt][r] * inv);
        }
}

// ---------------------------------------------------------------- launch
extern "C" void kernel_launch(void* const* d_in, const int* in_sizes, int n_in,
                              void* d_out, int out_size, void* d_ws, size_t ws_size,
                              hipStream_t stream) {
    const float* x    = (const float*)d_in[0];
    const float* cosT = (const float*)d_in[1];
    const float* sinT = (const float*)d_in[2];
    // d_in[3] = mask : causal, computed analytically — never read
    const float* Wqkv = (const float*)d_in[4];
    const float* Wout = (const float*)d_in[5];
    float* out = (float*)d_out;

    ushort* ws = (ushort*)d_ws;
    ushort* Xbf    = ws;                           // 8192*1024 (dead after GEMM0)
    ushort* WqkvT  = Xbf    + (size_t)MROWS * D_;  // 3072*1024
    ushort* WoutT  = WqkvT  + (size_t)3 * D_ * D_; // 1024*1024
    ushort* Qb     = WoutT  + (size_t)D_ * D_;     // 64*2048*64
    ushort* Kb     = Qb     + (size_t)BH_ * S_ * HD_;
    ushort* Vb     = Kb     + (size_t)BH_ * S_ * HD_;
    ushort* VbT    = Vb     + (size_t)BH_ * S_ * HD_;
    ushort* AO     = Xbf;                          // alias: Xbf dead after GEMM0

    k_prep<<<12288, 256, 0, stream>>>(x, Wqkv, Wout, Xbf, WqkvT, WoutT);
    k_gemm<0><<<dim3(3 * D_ / BN, MROWS / BM), 256, 0, stream>>>(Xbf, WqkvT, nullptr, Qb, Kb, Vb,
                                                                 MROWS, 3 * D_, D_);
    k_ropevt<<<34816, 256, 0, stream>>>(Qb, Kb, Vb, VbT, cosT, sinT);
    k_attn<<<1024, 256, 0, stream>>>(Qb, Kb, VbT, AO);
    k_gemm<1><<<dim3(D_ / BN, MROWS / BM), 256, 0, stream>>>(AO, WoutT, out, nullptr, nullptr, nullptr,
                                                             MROWS, D_, D_);
}